// Round 1
// baseline (12306.681 us; speedup 1.0000x reference)
//
#include <hip/hip_runtime.h>

// ---------------------------------------------------------------------------
// GLIFR RSNN on MI355X.
//
// Decomposition:
//   Kernel A: layer-0 GLIF scan. Elementwise per (b,n) neuron, sequential in t
//             only -> 8192 independent threads, software-pipelined input loads.
//             Writes S0_all[t,b,n] to workspace.
//   Kernel C: the recurrence. 256 WGs x 256 thr (1/CU, cooperative launch for
//             guaranteed co-residency) = 32 clusters (one per batch) x 8 WGs
//             (64 layer-1 neurons each). Weights held in REGISTERS for all
//             1000 steps (~192 VGPR/thread). Per step:
//               stage prev activations (atomic agent loads, MALL-coherent)
//               -> LDS (padded vs bank conflicts) -> fp32 dot products
//               -> shfl_xor k-reduction -> GLIF A then GLIF B (owner lanes)
//               -> sp_a/sp_b to d_out (sp_b via agent atomic stores =
//                  write-through, visible without cache flushes)
//               -> per-batch counter barrier (8 arrivals), monotonic target.
//             h2_t uses sp_b_{t-1} and h1_t uses S0_{t-1}: ONE barrier/step.
// ---------------------------------------------------------------------------

#define T_STEPS 1000
#define NB 32
#define N0 256
#define N1 512

// fp32 constants, folded exactly like the reference's python-float scalars
#define C_SYN_D 0.95f                      // 1 - DT*KSYN
#define C_SYN_I 0.05f                      // DT*KSYN
#define C_V_D   0.99f                      // 1 - DT*KM
#define C_KMR   0.0010604453870625663f     // DT*KM*R
#define C_TH    10.986122886681098f        // SIGMA_V * log((20-5)/5)
#define C_A0_D  0.99985f                   // 1 - DT*0.003
#define C_A0_I  (-0.459f)                  // -9.18*1.0*DT
#define C_A1_D  0.995f                     // 1 - DT*0.1
#define C_A1_I  (-9.947f)                  // -198.94*1.0*DT

__device__ __forceinline__ float glif_S(float V) {
  // 20 * sigmoid((V - TH)/10)
  return 20.0f / (1.0f + __expf((C_TH - V) * 0.1f));
}

// ---------------------------------------------------------------------------
// Kernel A: layer-0 scan. grid = 128 x 64. thread g = b*256 + n.
// Depth-8 software pipeline on the input loads (stride 32KB between steps).
// ---------------------------------------------------------------------------
__global__ __launch_bounds__(64)
void layer0_scan(const float* __restrict__ x, float* __restrict__ S0) {
  const int g = blockIdx.x * 64 + threadIdx.x;
  float V = 0.f, a0 = 0.f, a1 = 0.f, Is = 0.f;
  float xb[8];
#pragma unroll
  for (int i = 0; i < 8; ++i) xb[i] = x[i * (NB * N0) + g];
#pragma unroll 1
  for (int tb = 0; tb < T_STEPS / 8; ++tb) {
#pragma unroll
    for (int u = 0; u < 8; ++u) {
      const int t = tb * 8 + u;
      const float xi = xb[u];
      const int tf = t + 8;
      if (tf < T_STEPS) xb[u] = x[tf * (NB * N0) + g];
      Is = fmaf(Is, C_SYN_D, C_SYN_I * xi);
      V  = fmaf(V, C_V_D, C_KMR * (Is + a0 + a1));
      const float S = glif_S(V);
      a0 = fmaf(a0, C_A0_D, C_A0_I * S);
      a1 = fmaf(a1, C_A1_D, C_A1_I * S);
      S0[t * (NB * N0) + g] = S;
    }
  }
}

// ---------------------------------------------------------------------------
// Kernel C: recurrence. grid = 256 x 256 (cooperative).
// wg = b*8 + s; m-slice = [s*64, s*64+64). tid = mg*16 + kc:
//   mg in [0,16): group of 4 consecutive m;  kc in [0,16): K-chunk.
// Per thread: Wr chunk 4m x 32k (32 float4 regs), W1 chunk 4m x 16k (16 float4).
// LDS activation staging padded: 32-word chunks stored at stride 36 words
// (16B-aligned), 16-word chunks at stride 20 -> stride-32 b128 reads become
// conflict-free (2 lanes/bank).
// ---------------------------------------------------------------------------
__global__ __launch_bounds__(256, 1)
void rsnn_recur(const float* __restrict__ W1, const float* __restrict__ Wr,
                const float* __restrict__ S0, float* __restrict__ out,
                unsigned* __restrict__ bar) {
  const int wg  = blockIdx.x;
  const int b   = wg >> 3;
  const int s   = wg & 7;
  const int tid = threadIdx.x;
  const int mg  = tid >> 4;
  const int kc  = tid & 15;
  const int mBase = s * 64 + mg * 4;

  __shared__ float actS[16 * 36];   // 512 spb values, padded
  __shared__ float actO[16 * 20];   // 256 S0 values, padded

  // --- one-time weight load into registers ---
  float4 wr4[4][8];
  float4 w14[4][4];
#pragma unroll
  for (int i = 0; i < 4; ++i) {
    const float4* rw = (const float4*)(Wr + (size_t)(mBase + i) * N1 + kc * 32);
#pragma unroll
    for (int j = 0; j < 8; ++j) wr4[i][j] = rw[j];
    const float4* r1 = (const float4*)(W1 + (size_t)(mBase + i) * N0 + kc * 16);
#pragma unroll
    for (int j = 0; j < 4; ++j) w14[i][j] = r1[j];
  }

  float V[4]   = {0.f, 0.f, 0.f, 0.f};
  float A0v[4] = {0.f, 0.f, 0.f, 0.f};
  float A1v[4] = {0.f, 0.f, 0.f, 0.f};
  float Is[4]  = {0.f, 0.f, 0.f, 0.f};
  unsigned* cnt = bar + b;

#pragma unroll 1
  for (int t = 0; t < T_STEPS; ++t) {
    // ---- stage previous activations into LDS ----
    if (t == 0) {
      actS[(tid >> 5) * 36 + (tid & 31)] = 0.f;
      {
        const int k = tid + 256;
        actS[(k >> 5) * 36 + (k & 31)] = 0.f;
      }
      actO[(tid >> 4) * 20 + (tid & 15)] = 0.f;
    } else {
      const float* pS = out + ((size_t)(2 * t - 1) * NB + b) * N1;
      const float v0 = __hip_atomic_load(pS + tid,       __ATOMIC_RELAXED, __HIP_MEMORY_SCOPE_AGENT);
      const float v1 = __hip_atomic_load(pS + tid + 256, __ATOMIC_RELAXED, __HIP_MEMORY_SCOPE_AGENT);
      const float v2 = S0[(size_t)(t - 1) * (NB * N0) + b * N0 + tid];
      actS[(tid >> 5) * 36 + (tid & 31)] = v0;
      {
        const int k = tid + 256;
        actS[(k >> 5) * 36 + (k & 31)] = v1;
      }
      actO[(tid >> 4) * 20 + (tid & 15)] = v2;
    }
    __syncthreads();

    // ---- partial dot products (weights from registers, acts from LDS) ----
    float h2a[4] = {0.f, 0.f, 0.f, 0.f};
    float h1a[4] = {0.f, 0.f, 0.f, 0.f};
    const float4* aS4 = (const float4*)actS;
    const float4* aO4 = (const float4*)actO;
#pragma unroll
    for (int j = 0; j < 8; ++j) {
      const float4 a = aS4[kc * 9 + j];
#pragma unroll
      for (int i = 0; i < 4; ++i) {
        h2a[i] = fmaf(wr4[i][j].x, a.x, h2a[i]);
        h2a[i] = fmaf(wr4[i][j].y, a.y, h2a[i]);
        h2a[i] = fmaf(wr4[i][j].z, a.z, h2a[i]);
        h2a[i] = fmaf(wr4[i][j].w, a.w, h2a[i]);
      }
    }
#pragma unroll
    for (int j = 0; j < 4; ++j) {
      const float4 a = aO4[kc * 5 + j];
#pragma unroll
      for (int i = 0; i < 4; ++i) {
        h1a[i] = fmaf(w14[i][j].x, a.x, h1a[i]);
        h1a[i] = fmaf(w14[i][j].y, a.y, h1a[i]);
        h1a[i] = fmaf(w14[i][j].z, a.z, h1a[i]);
        h1a[i] = fmaf(w14[i][j].w, a.w, h1a[i]);
      }
    }

    // ---- reduce across the 16 k-chunks (low 4 lane bits) ----
#pragma unroll
    for (int mask = 1; mask <= 8; mask <<= 1) {
#pragma unroll
      for (int i = 0; i < 4; ++i) {
        h2a[i] += __shfl_xor(h2a[i], mask, 64);
        h1a[i] += __shfl_xor(h1a[i], mask, 64);
      }
    }

    // ---- owner lanes: GLIF A (h1) then GLIF B (h2), write spikes ----
    if (kc == 0) {
      float spa[4], spb[4];
#pragma unroll
      for (int i = 0; i < 4; ++i) {
        Is[i] = fmaf(Is[i], C_SYN_D, C_SYN_I * h1a[i]);
        V[i]  = fmaf(V[i], C_V_D, C_KMR * (Is[i] + A0v[i] + A1v[i]));
        const float Sa = glif_S(V[i]);
        A0v[i] = fmaf(A0v[i], C_A0_D, C_A0_I * Sa);
        A1v[i] = fmaf(A1v[i], C_A1_D, C_A1_I * Sa);
        spa[i] = Sa;
        Is[i] = fmaf(Is[i], C_SYN_D, C_SYN_I * h2a[i]);
        V[i]  = fmaf(V[i], C_V_D, C_KMR * (Is[i] + A0v[i] + A1v[i]));
        const float Sb = glif_S(V[i]);
        A0v[i] = fmaf(A0v[i], C_A0_D, C_A0_I * Sb);
        A1v[i] = fmaf(A1v[i], C_A1_D, C_A1_I * Sb);
        spb[i] = Sb;
      }
      float* outA = out + ((size_t)(2 * t) * NB + b) * N1 + mBase;
      *(float4*)outA = make_float4(spa[0], spa[1], spa[2], spa[3]);
      float* outB = out + ((size_t)(2 * t + 1) * NB + b) * N1 + mBase;
#pragma unroll
      for (int i = 0; i < 4; ++i)
        __hip_atomic_store(outB + i, spb[i], __ATOMIC_RELAXED, __HIP_MEMORY_SCOPE_AGENT);
    }

    // ---- per-batch cluster barrier (8 WGs), monotonic counter ----
    if (t < T_STEPS - 1) {
      __syncthreads();  // compiler emits s_waitcnt vmcnt(0) before s_barrier:
                        // all lanes' write-through spb stores are globally
                        // visible before the flag increment below.
      if (tid == 0) {
        __hip_atomic_fetch_add(cnt, 1u, __ATOMIC_RELAXED, __HIP_MEMORY_SCOPE_AGENT);
        const unsigned tgt = 8u * (unsigned)(t + 1);
        while (__hip_atomic_load(cnt, __ATOMIC_RELAXED, __HIP_MEMORY_SCOPE_AGENT) < tgt) {}
      }
      __syncthreads();
    }
  }
}

// ---------------------------------------------------------------------------
extern "C" void kernel_launch(void* const* d_in, const int* in_sizes, int n_in,
                              void* d_out, int out_size, void* d_ws, size_t ws_size,
                              hipStream_t stream) {
  const float* inputs = (const float*)d_in[0];   // [1000,32,1,256]
  const float* W1     = (const float*)d_in[1];   // [512,256]
  const float* Wr     = (const float*)d_in[2];   // [512,512]
  float* out = (float*)d_out;                    // [2000,32,1,512]

  float* S0 = (float*)d_ws;                                        // 32,768,000 B
  unsigned* bar = (unsigned*)((char*)d_ws +
                              (size_t)T_STEPS * NB * N0 * sizeof(float));

  // barrier counters must start at 0 every call (ws is re-poisoned to 0xAA)
  hipMemsetAsync(bar, 0, NB * sizeof(unsigned), stream);

  hipLaunchKernelGGL(layer0_scan, dim3((NB * N0) / 64), dim3(64), 0, stream,
                     inputs, S0);

  void* args[5];
  args[0] = (void*)&W1;
  args[1] = (void*)&Wr;
  args[2] = (void*)&S0;
  args[3] = (void*)&out;
  args[4] = (void*)&bar;
  // Cooperative launch: guarantees all 256 WGs (1/CU) co-resident, so the
  // per-batch spin barriers cannot deadlock.
  hipLaunchCooperativeKernel((const void*)rsnn_recur, dim3(256), dim3(256),
                             args, 0, stream);
}

// Round 5
// 2827.678 us; speedup vs baseline: 4.3522x; 4.3522x over previous
//
#include <hip/hip_runtime.h>

// ---------------------------------------------------------------------------
// GLIFR RSNN on MI355X — round 5: r1 (proven-running) + per-batch counter
// cache lines. BYTE-MINIMAL delta from round 1.
//
// History:
//   r1 (PASSED, 11.75ms): counter-barrier per batch; all 32 counters in ONE
//      128B line -> 256 fetch_adds + 32 spinners serialize on that line
//      (~10us/step). VALUBusy 4.4%, HBM 0.8%, MfmaUtil 0 -> pure latency.
//   r2/r3/r4 (FAILED, kernel never ran): test returns in ~2.7s with
//      hipStreamSynchronize SUCCEEDING and d_out all zero -> the launches
//      inside kernel_launch (unchecked return) failed; streams stayed empty.
//      Common to all three: restructured spin machinery (per-thread data
//      polls / __syncthreads_and vote / per-lane flag spins). Root cause not
//      identified; r1's exact structure is the only one proven to launch.
//   r5: r1 verbatim EXCEPT bar[b] -> bar[b*32]: one 128B line per batch
//      (8 fetch_adds + 1 spinner per line per step instead of 256 + 32 on
//      one line). Single isolated variable.
//
//   Kernel A (layer0_scan): layer-0 GLIF scan, elementwise per (b,n) neuron;
//     stream-ordered before kernel C -> C reads S0 with plain cached loads.
//   Kernel C (rsnn_recur): 256 WGs x 256 thr (cooperative, 1 WG/CU) = 32
//     clusters (batch) x 8 WGs (64 neurons). Weights in registers for all
//     1000 steps. h1_t uses S0_{t-1}, h2_t uses spb_{t-1} -> one sync/step.
//
// NOTE (r2/r3 lesson, keep for future rounds): fp32 S is EXACTLY 0.0 for
// strongly inhibited neurons (a1 ~ -1e4 -> V ~ -1050 -> __expf overflow ->
// 20/inf = 0), identically in the jax reference. Output values 0x00000000
// are legitimate — never use them as "not ready" sentinels.
// ---------------------------------------------------------------------------

#define T_STEPS 1000
#define NB 32
#define N0 256
#define N1 512

// fp32 constants, folded exactly like the reference's python-float scalars
#define C_SYN_D 0.95f                      // 1 - DT*KSYN
#define C_SYN_I 0.05f                      // DT*KSYN
#define C_V_D   0.99f                      // 1 - DT*KM
#define C_KMR   0.0010604453870625663f     // DT*KM*R
#define C_TH    10.986122886681098f        // SIGMA_V * log((20-5)/5)
#define C_A0_D  0.99985f                   // 1 - DT*0.003
#define C_A0_I  (-0.459f)                  // -9.18*1.0*DT
#define C_A1_D  0.995f                     // 1 - DT*0.1
#define C_A1_I  (-9.947f)                  // -198.94*1.0*DT

__device__ __forceinline__ float glif_S(float V) {
  // 20 * sigmoid((V - TH)/10)
  return 20.0f / (1.0f + __expf((C_TH - V) * 0.1f));
}

// ---------------------------------------------------------------------------
// Kernel A: layer-0 scan. grid = 128 x 64. thread g = b*256 + n.
// Depth-8 software pipeline on the input loads (stride 32KB between steps).
// ---------------------------------------------------------------------------
__global__ __launch_bounds__(64)
void layer0_scan(const float* __restrict__ x, float* __restrict__ S0) {
  const int g = blockIdx.x * 64 + threadIdx.x;
  float V = 0.f, a0 = 0.f, a1 = 0.f, Is = 0.f;
  float xb[8];
#pragma unroll
  for (int i = 0; i < 8; ++i) xb[i] = x[i * (NB * N0) + g];
#pragma unroll 1
  for (int tb = 0; tb < T_STEPS / 8; ++tb) {
#pragma unroll
    for (int u = 0; u < 8; ++u) {
      const int t = tb * 8 + u;
      const float xi = xb[u];
      const int tf = t + 8;
      if (tf < T_STEPS) xb[u] = x[tf * (NB * N0) + g];
      Is = fmaf(Is, C_SYN_D, C_SYN_I * xi);
      V  = fmaf(V, C_V_D, C_KMR * (Is + a0 + a1));
      const float S = glif_S(V);
      a0 = fmaf(a0, C_A0_D, C_A0_I * S);
      a1 = fmaf(a1, C_A1_D, C_A1_I * S);
      S0[t * (NB * N0) + g] = S;
    }
  }
}

// ---------------------------------------------------------------------------
// Kernel C: recurrence. grid = 256 x 256 (cooperative).
// wg = b*8 + s; m-slice = [s*64, s*64+64). tid = mg*16 + kc:
//   mg in [0,16): group of 4 consecutive m;  kc in [0,16): K-chunk.
// Per thread: Wr chunk 4m x 32k (32 float4 regs), W1 chunk 4m x 16k (16 float4).
// LDS activation staging padded: 32-word chunks stored at stride 36 words
// (16B-aligned), 16-word chunks at stride 20 -> stride-32 b128 reads become
// conflict-free (2 lanes/bank).
// ---------------------------------------------------------------------------
__global__ __launch_bounds__(256, 1)
void rsnn_recur(const float* __restrict__ W1, const float* __restrict__ Wr,
                const float* __restrict__ S0, float* __restrict__ out,
                unsigned* __restrict__ bar) {
  const int wg  = blockIdx.x;
  const int b   = wg >> 3;
  const int s   = wg & 7;
  const int tid = threadIdx.x;
  const int mg  = tid >> 4;
  const int kc  = tid & 15;
  const int mBase = s * 64 + mg * 4;

  __shared__ float actS[16 * 36];   // 512 spb values, padded
  __shared__ float actO[16 * 20];   // 256 S0 values, padded

  // --- one-time weight load into registers ---
  float4 wr4[4][8];
  float4 w14[4][4];
#pragma unroll
  for (int i = 0; i < 4; ++i) {
    const float4* rw = (const float4*)(Wr + (size_t)(mBase + i) * N1 + kc * 32);
#pragma unroll
    for (int j = 0; j < 8; ++j) wr4[i][j] = rw[j];
    const float4* r1 = (const float4*)(W1 + (size_t)(mBase + i) * N0 + kc * 16);
#pragma unroll
    for (int j = 0; j < 4; ++j) w14[i][j] = r1[j];
  }

  float V[4]   = {0.f, 0.f, 0.f, 0.f};
  float A0v[4] = {0.f, 0.f, 0.f, 0.f};
  float A1v[4] = {0.f, 0.f, 0.f, 0.f};
  float Is[4]  = {0.f, 0.f, 0.f, 0.f};
  // r5 CHANGE (the only one): one 128B cache line per batch's counter.
  unsigned* cnt = bar + b * 32;

#pragma unroll 1
  for (int t = 0; t < T_STEPS; ++t) {
    // ---- stage previous activations into LDS ----
    if (t == 0) {
      actS[(tid >> 5) * 36 + (tid & 31)] = 0.f;
      {
        const int k = tid + 256;
        actS[(k >> 5) * 36 + (k & 31)] = 0.f;
      }
      actO[(tid >> 4) * 20 + (tid & 15)] = 0.f;
    } else {
      const float* pS = out + ((size_t)(2 * t - 1) * NB + b) * N1;
      const float v0 = __hip_atomic_load(pS + tid,       __ATOMIC_RELAXED, __HIP_MEMORY_SCOPE_AGENT);
      const float v1 = __hip_atomic_load(pS + tid + 256, __ATOMIC_RELAXED, __HIP_MEMORY_SCOPE_AGENT);
      const float v2 = S0[(size_t)(t - 1) * (NB * N0) + b * N0 + tid];
      actS[(tid >> 5) * 36 + (tid & 31)] = v0;
      {
        const int k = tid + 256;
        actS[(k >> 5) * 36 + (k & 31)] = v1;
      }
      actO[(tid >> 4) * 20 + (tid & 15)] = v2;
    }
    __syncthreads();

    // ---- partial dot products (weights from registers, acts from LDS) ----
    float h2a[4] = {0.f, 0.f, 0.f, 0.f};
    float h1a[4] = {0.f, 0.f, 0.f, 0.f};
    const float4* aS4 = (const float4*)actS;
    const float4* aO4 = (const float4*)actO;
#pragma unroll
    for (int j = 0; j < 8; ++j) {
      const float4 a = aS4[kc * 9 + j];
#pragma unroll
      for (int i = 0; i < 4; ++i) {
        h2a[i] = fmaf(wr4[i][j].x, a.x, h2a[i]);
        h2a[i] = fmaf(wr4[i][j].y, a.y, h2a[i]);
        h2a[i] = fmaf(wr4[i][j].z, a.z, h2a[i]);
        h2a[i] = fmaf(wr4[i][j].w, a.w, h2a[i]);
      }
    }
#pragma unroll
    for (int j = 0; j < 4; ++j) {
      const float4 a = aO4[kc * 5 + j];
#pragma unroll
      for (int i = 0; i < 4; ++i) {
        h1a[i] = fmaf(w14[i][j].x, a.x, h1a[i]);
        h1a[i] = fmaf(w14[i][j].y, a.y, h1a[i]);
        h1a[i] = fmaf(w14[i][j].z, a.z, h1a[i]);
        h1a[i] = fmaf(w14[i][j].w, a.w, h1a[i]);
      }
    }

    // ---- reduce across the 16 k-chunks (low 4 lane bits) ----
#pragma unroll
    for (int mask = 1; mask <= 8; mask <<= 1) {
#pragma unroll
      for (int i = 0; i < 4; ++i) {
        h2a[i] += __shfl_xor(h2a[i], mask, 64);
        h1a[i] += __shfl_xor(h1a[i], mask, 64);
      }
    }

    // ---- owner lanes: GLIF A (h1) then GLIF B (h2), write spikes ----
    if (kc == 0) {
      float spa[4], spb[4];
#pragma unroll
      for (int i = 0; i < 4; ++i) {
        Is[i] = fmaf(Is[i], C_SYN_D, C_SYN_I * h1a[i]);
        V[i]  = fmaf(V[i], C_V_D, C_KMR * (Is[i] + A0v[i] + A1v[i]));
        const float Sa = glif_S(V[i]);
        A0v[i] = fmaf(A0v[i], C_A0_D, C_A0_I * Sa);
        A1v[i] = fmaf(A1v[i], C_A1_D, C_A1_I * Sa);
        spa[i] = Sa;
        Is[i] = fmaf(Is[i], C_SYN_D, C_SYN_I * h2a[i]);
        V[i]  = fmaf(V[i], C_V_D, C_KMR * (Is[i] + A0v[i] + A1v[i]));
        const float Sb = glif_S(V[i]);
        A0v[i] = fmaf(A0v[i], C_A0_D, C_A0_I * Sb);
        A1v[i] = fmaf(A1v[i], C_A1_D, C_A1_I * Sb);
        spb[i] = Sb;
      }
      float* outA = out + ((size_t)(2 * t) * NB + b) * N1 + mBase;
      *(float4*)outA = make_float4(spa[0], spa[1], spa[2], spa[3]);
      float* outB = out + ((size_t)(2 * t + 1) * NB + b) * N1 + mBase;
#pragma unroll
      for (int i = 0; i < 4; ++i)
        __hip_atomic_store(outB + i, spb[i], __ATOMIC_RELAXED, __HIP_MEMORY_SCOPE_AGENT);
    }

    // ---- per-batch cluster barrier (8 WGs), monotonic counter ----
    if (t < T_STEPS - 1) {
      __syncthreads();  // compiler emits s_waitcnt vmcnt(0) before s_barrier:
                        // all lanes' write-through spb stores are globally
                        // visible before the flag increment below.
      if (tid == 0) {
        __hip_atomic_fetch_add(cnt, 1u, __ATOMIC_RELAXED, __HIP_MEMORY_SCOPE_AGENT);
        const unsigned tgt = 8u * (unsigned)(t + 1);
        while (__hip_atomic_load(cnt, __ATOMIC_RELAXED, __HIP_MEMORY_SCOPE_AGENT) < tgt) {}
      }
      __syncthreads();
    }
  }
}

// ---------------------------------------------------------------------------
extern "C" void kernel_launch(void* const* d_in, const int* in_sizes, int n_in,
                              void* d_out, int out_size, void* d_ws, size_t ws_size,
                              hipStream_t stream) {
  const float* inputs = (const float*)d_in[0];   // [1000,32,1,256]
  const float* W1     = (const float*)d_in[1];   // [512,256]
  const float* Wr     = (const float*)d_in[2];   // [512,512]
  float* out = (float*)d_out;                    // [2000,32,1,512]

  float* S0 = (float*)d_ws;                                        // 32,768,000 B
  unsigned* bar = (unsigned*)((char*)d_ws +
                              (size_t)T_STEPS * NB * N0 * sizeof(float));

  // barrier counters must start at 0 every call (ws is re-poisoned to 0xAA);
  // 32 batches x 32 words = 4KB, one 128B line per batch.
  hipMemsetAsync(bar, 0, NB * 32 * sizeof(unsigned), stream);

  hipLaunchKernelGGL(layer0_scan, dim3((NB * N0) / 64), dim3(64), 0, stream,
                     inputs, S0);

  void* args[5];
  args[0] = (void*)&W1;
  args[1] = (void*)&Wr;
  args[2] = (void*)&S0;
  args[3] = (void*)&out;
  args[4] = (void*)&bar;
  // Cooperative launch: guarantees all 256 WGs (1/CU) co-resident, so the
  // per-batch spin barriers cannot deadlock.
  hipLaunchCooperativeKernel((const void*)rsnn_recur, dim3(256), dim3(256),
                             args, 0, stream);
}